// Round 11
// baseline (190.545 us; speedup 1.0000x reference)
//
#include <hip/hip_runtime.h>
#include <hip/hip_bf16.h>

// Problem constants
#define BB 2
#define SS 2048
#define HH 1024
#define NHH 16
#define HDD 64
#define MM (BB*SS)        // 4096
#define QKV_N (3*HH)      // 3072

typedef _Float16 f16x8 __attribute__((ext_vector_type(8)));
typedef _Float16 f16x4 __attribute__((ext_vector_type(4)));
typedef float f32x4 __attribute__((ext_vector_type(4)));

#define MFMA16(a,b,c)  __builtin_amdgcn_mfma_f32_16x16x32_f16((a),(b),(c),0,0,0)
#define MFMA16K16(a,b,c) __builtin_amdgcn_mfma_f32_16x16x16f16((a),(b),(c),0,0,0)

// async global->LDS 16B per lane; LDS dest = wave-uniform base + lane*16
__device__ __forceinline__ void gl2lds16(const _Float16* g, _Float16* l) {
    __builtin_amdgcn_global_load_lds(
        (const __attribute__((address_space(1))) void*)g,
        (__attribute__((address_space(3))) void*)l, 16, 0, 0);
}

// single-instruction exp2 WITH compiler hazard handling (raw asm broke TRANS-op waits)
__device__ __forceinline__ float fexp2(float x) { return __builtin_amdgcn_exp2f(x); }

// ---------------- prep: z<4 transpose-cast W -> Wt fp16; z==4 cast X -> fp16 ------------
// grid (16,16,5), block 256.
__global__ __launch_bounds__(256) void prep_kernel(
    const float* __restrict__ X,
    const float* __restrict__ W0, const float* __restrict__ W1,
    const float* __restrict__ W2, const float* __restrict__ W3,
    _Float16* __restrict__ Xh,
    _Float16* __restrict__ WqkvT, _Float16* __restrict__ WoT)
{
    __shared__ float t[64][65];
    int z = blockIdx.z;
    int tid = threadIdx.x;
    if (z == 4) {
        int base = (blockIdx.y * 16 + blockIdx.x) * 256 + tid;
        const float4* xin = (const float4*)X;
        f16x4* xout = (f16x4*)Xh;
#pragma unroll
        for (int i = 0; i < 16; ++i) {
            float4 v = xin[base + i * 65536];
            f16x4 hh = {(_Float16)v.x, (_Float16)v.y, (_Float16)v.z, (_Float16)v.w};
            xout[base + i * 65536] = hh;
        }
        return;
    }
    const float* src = (z == 0) ? W0 : (z == 1) ? W1 : (z == 2) ? W2 : W3;
    _Float16* dst = (z < 3) ? (WqkvT + (size_t)z * HH * HH) : WoT;
    int k0 = blockIdx.y * 64, n0 = blockIdx.x * 64;
#pragma unroll
    for (int p = 0; p < 4; ++p) {
        int row = p * 16 + (tid >> 4);
        int col4 = (tid & 15) * 4;
        float4 v = *(const float4*)&src[(size_t)(k0 + row) * HH + n0 + col4];
        t[row][col4 + 0] = v.x; t[row][col4 + 1] = v.y;
        t[row][col4 + 2] = v.z; t[row][col4 + 3] = v.w;
    }
    __syncthreads();
#pragma unroll
    for (int p = 0; p < 2; ++p) {
        int nc = p * 32 + (tid >> 3);
        int ch = tid & 7;
        f16x8 o;
#pragma unroll
        for (int j = 0; j < 8; ++j) o[j] = (_Float16)t[ch * 8 + j][nc];
        *(f16x8*)&dst[(size_t)(n0 + nc) * HH + k0 + ch * 8] = o;
    }
}

// ---------------- QKV GEMM: 128x128 tile, 3-stage pipeline (proven 43.5us, FINAL) -------
__global__ __launch_bounds__(256) void gemm_qkv_kernel(
    const _Float16* __restrict__ A, const _Float16* __restrict__ Bt,
    const float* __restrict__ bias0, const float* __restrict__ bias1, const float* __restrict__ bias2,
    _Float16* __restrict__ Qh, _Float16* __restrict__ Kh, _Float16* __restrict__ Vt)
{
    const int K = HH;
    const int NT = K / 32;
    __shared__ _Float16 smem[24576];          // 49152 B: 3-stage bufs U epilogue tile 128x132

    int row0 = blockIdx.y * 128, n0 = blockIdx.x * 128;
    int tid = threadIdx.x;
    int w = tid >> 6, l = tid & 63, m16 = l & 15, quad = l >> 4;
    int wm = w >> 1, wn = w & 1;

    int srow = w * 32 + (l >> 2);
    int sch = (l & 3) ^ ((l >> 2) & 3) ^ ((l >> 4) & 3);
    const _Float16* aptr = A + (size_t)(row0 + srow) * K + sch * 8;
    const _Float16* bptr = Bt + (size_t)(n0 + srow) * K + sch * 8;

    int gsw = (m16 & 3) ^ ((m16 >> 2) & 3);
    int acol = (quad ^ gsw) * 8;

    f32x4 zero4 = {0.f, 0.f, 0.f, 0.f};
    f32x4 acc[4][4];
#pragma unroll
    for (int i = 0; i < 4; ++i)
#pragma unroll
        for (int j = 0; j < 4; ++j) acc[i][j] = zero4;

    auto stage = [&](int t, int s) {
        int k0 = t * 32;
        int ao = s * 4096 + (w * 32) * 32;
        int bo = 12288 + s * 4096 + (w * 32) * 32;
        gl2lds16(aptr + k0, smem + ao);
        gl2lds16(aptr + (size_t)16 * K + k0, smem + ao + 16 * 32);
        gl2lds16(bptr + k0, smem + bo);
        gl2lds16(bptr + (size_t)16 * K + k0, smem + bo + 16 * 32);
    };

    stage(0, 0);
    stage(1, 1);
    int cur = 0;
    for (int t = 0; t < NT; ++t) {
        if (t < NT - 1) asm volatile("s_waitcnt vmcnt(4)" ::: "memory");
        else            asm volatile("s_waitcnt vmcnt(0)" ::: "memory");
        asm volatile("s_barrier" ::: "memory");
        if (t + 2 < NT) {
            int nxt = cur + 2; if (nxt >= 3) nxt -= 3;
            stage(t + 2, nxt);
        }
        const _Float16* Asr = smem + cur * 4096;
        const _Float16* Bsr = smem + 12288 + cur * 4096;
        f16x8 af[4], bf[4];
#pragma unroll
        for (int i = 0; i < 4; ++i)
            af[i] = *(const f16x8*)&Asr[(wm * 64 + i * 16 + m16) * 32 + acol];
#pragma unroll
        for (int j = 0; j < 4; ++j)
            bf[j] = *(const f16x8*)&Bsr[(wn * 64 + j * 16 + m16) * 32 + acol];
#pragma unroll
        for (int i = 0; i < 4; ++i)
#pragma unroll
            for (int j = 0; j < 4; ++j)
                acc[i][j] = MFMA16(af[i], bf[j], acc[i][j]);
        cur = (cur == 2) ? 0 : cur + 1;
    }

    // ---- epilogue: bias (+scale for Q), LDS bounce, coalesced stores ----
    int which = n0 >> 10;                     // 0=Q 1=K 2=V (block is pure)
    const float* bias = (which == 0) ? bias0 : (which == 1) ? bias1 : bias2;
    __syncthreads();
#pragma unroll
    for (int j = 0; j < 4; ++j) {
        int n_local = wn * 64 + j * 16 + m16;
        float bi = bias[(n0 + n_local) & 1023];
#pragma unroll
        for (int i = 0; i < 4; ++i)
#pragma unroll
            for (int r = 0; r < 4; ++r) {
                int m_local = wm * 64 + i * 16 + quad * 4 + r;
                float v = acc[i][j][r] + bi;
                if (which == 0) v *= 0.18033688011112042f;  // (1/sqrt(64))*log2(e)
                if (which == 2) smem[n_local * 132 + m_local] = (_Float16)v;   // transposed
                else            smem[m_local * 132 + n_local] = (_Float16)v;
            }
    }
    __syncthreads();

    int b = row0 >> 11, s0 = row0 & 2047;
    if (which == 2) {
#pragma unroll
        for (int p = 0; p < 8; ++p) {
            int n_local = p * 16 + (tid >> 4);
            int schunk = tid & 15;
            f16x8 v = *(const f16x8*)&smem[n_local * 132 + schunk * 8];
            int nw = (n0 + n_local) & 1023;
            int hh = nw >> 6, d = nw & 63;
            *(f16x8*)&Vt[((size_t)(b * NHH + hh) * HDD + d) * SS + s0 + schunk * 8] = v;
        }
    } else {
        _Float16* dst = (which == 0) ? Qh : Kh;
        int hh0 = (n0 & 1023) >> 6;
#pragma unroll
        for (int p = 0; p < 8; ++p) {
            int m_local = p * 16 + (tid >> 4);
            int seg = tid & 15;
            f16x8 v = *(const f16x8*)&smem[m_local * 132 + seg * 8];
            int hh = hh0 + (seg >> 3), d = (seg & 7) * 8;
            *(f16x8*)&dst[((size_t)(b * NHH + hh) * SS + s0 + m_local) * HDD + d] = v;
        }
    }
}

// ---------------- Output projection: 128x128 tile, split-K WITHIN block (proven R10) ----
__global__ __launch_bounds__(512, 2) void gemm_out_kernel(
    const _Float16* __restrict__ A, const _Float16* __restrict__ Bt,
    const float* __restrict__ bias0, float* __restrict__ Out)
{
    const int K = HH;
    const int NT = 16;                        // 16 x 32 = 512 of K per group
    __shared__ _Float16 smem[49152];          // 98304 B: group g 3-stage bufs at g*24576

    int row0 = blockIdx.y * 128, n0 = blockIdx.x * 128;
    int tid = threadIdx.x;
    int w = tid >> 6, l = tid & 63, m16 = l & 15, quad = l >> 4;
    int kg = w >> 2, wl = w & 3;              // K-group, wave-in-group
    int wm = wl >> 1, wn = wl & 1;
    int kbase = kg * 512;
    _Float16* gsm = smem + kg * 24576;

    int srow = wl * 32 + (l >> 2);
    int sch = (l & 3) ^ ((l >> 2) & 3) ^ ((l >> 4) & 3);
    const _Float16* aptr = A + (size_t)(row0 + srow) * K + kbase + sch * 8;
    const _Float16* bptr = Bt + (size_t)(n0 + srow) * K + kbase + sch * 8;

    int gsw = (m16 & 3) ^ ((m16 >> 2) & 3);
    int acol = (quad ^ gsw) * 8;

    f32x4 zero4 = {0.f, 0.f, 0.f, 0.f};
    f32x4 acc[4][4];
#pragma unroll
    for (int i = 0; i < 4; ++i)
#pragma unroll
        for (int j = 0; j < 4; ++j) acc[i][j] = zero4;

    auto stage = [&](int t, int s) {
        int k0 = t * 32;
        int ao = s * 4096 + (wl * 32) * 32;
        int bo = 12288 + s * 4096 + (wl * 32) * 32;
        gl2lds16(aptr + k0, gsm + ao);
        gl2lds16(aptr + (size_t)16 * K + k0, gsm + ao + 16 * 32);
        gl2lds16(bptr + k0, gsm + bo);
        gl2lds16(bptr + (size_t)16 * K + k0, gsm + bo + 16 * 32);
    };

    stage(0, 0);
    stage(1, 1);
    int cur = 0;
    for (int t = 0; t < NT; ++t) {
        if (t < NT - 1) asm volatile("s_waitcnt vmcnt(4)" ::: "memory");
        else            asm volatile("s_waitcnt vmcnt(0)" ::: "memory");
        asm volatile("s_barrier" ::: "memory");
        if (t + 2 < NT) {
            int nxt = cur + 2; if (nxt >= 3) nxt -= 3;
            stage(t + 2, nxt);
        }
        const _Float16* Asr = gsm + cur * 4096;
        const _Float16* Bsr = gsm + 12288 + cur * 4096;
        f16x8 af[4], bf[4];
#pragma unroll
        for (int i = 0; i < 4; ++i)
            af[i] = *(const f16x8*)&Asr[(wm * 64 + i * 16 + m16) * 32 + acol];
#pragma unroll
        for (int j = 0; j < 4; ++j)
            bf[j] = *(const f16x8*)&Bsr[(wn * 64 + j * 16 + m16) * 32 + acol];
#pragma unroll
        for (int i = 0; i < 4; ++i)
#pragma unroll
            for (int j = 0; j < 4; ++j)
                acc[i][j] = MFMA16(af[i], bf[j], acc[i][j]);
        cur = (cur == 2) ? 0 : cur + 1;
    }

    // ---- cross-group reduce: stride-65 f32 slots (conflict-free scalar access) ----
    float* red = (float*)smem;                // 256 lanes x 65 f32 = 66560 B < 98304
    __syncthreads();                          // all waves done with staging-buffer reads
    if (kg == 1) {
        float* slot = red + (size_t)(wl * 64 + l) * 65;
#pragma unroll
        for (int i = 0; i < 4; ++i)
#pragma unroll
            for (int j = 0; j < 4; ++j)
#pragma unroll
                for (int r = 0; r < 4; ++r)
                    slot[i * 16 + j * 4 + r] = acc[i][j][r];
    }
    __syncthreads();
    if (kg == 0) {
        const float* slot = red + (size_t)(wl * 64 + l) * 65;
#pragma unroll
        for (int j = 0; j < 4; ++j) {
            int n = n0 + wn * 64 + j * 16 + m16;
            float bi = bias0[n];
#pragma unroll
            for (int i = 0; i < 4; ++i)
#pragma unroll
                for (int r = 0; r < 4; ++r) {
                    int mg = row0 + wm * 64 + i * 16 + quad * 4 + r;
                    Out[(size_t)mg * HH + n] = acc[i][j][r] + slot[i * 16 + j * 4 + r] + bi;
                }
        }
    }
}

// ---------------- Flash attention: S^T, paired tiles + A-wave helper slice-split --------
// grid (16, NH, B), block 512 (8 waves). Waves 0-3 own tile tA=bx, waves 4-7 own
// tB=31-tA. NEW: instead of idling for t > tA (33% of wave-time), A-waves finish tA at
// t==tA (normalize + store mid-loop, freeing o/lacc — never dual accumulator state, the
// R6 spill culprit), swap in prefetched qB Q-frags (+16 VGPR), and for t > tA the qB
// body is SLICE-SPLIT: A-wave key-slices {0,1}, B-wave {2,3} (pure sums -> associative);
// partials merged by a once-per-kernel stride-17 LDS reduce. body(slo,shi) called with
// literal args so the compiler prunes slices. Mask applied unconditionally (provably
// inert off-diagonal: keys <= t*64+63 < q for t below the tile).
__global__ __launch_bounds__(512, 4) void attn_kernel(
    const _Float16* __restrict__ Qh, const _Float16* __restrict__ Kh,
    const _Float16* __restrict__ Vt, _Float16* __restrict__ Ctx)
{
    __shared__ _Float16 KV[3 * 8192];     // 49152 B, 3-stage K+V (reduce area reuses buf 0)

    int tid = threadIdx.x;
    int w = tid >> 6, l = tid & 63;
    int m16 = l & 15, quad = l >> 4;
    int b = blockIdx.z, h = blockIdx.y;
    int tA = blockIdx.x, tB = 31 - tA;
    int half = w >> 2, wq = w & 3;
    int myT = half ? tB : tA;             // this wave's initial q-tile index

    const _Float16* Q = Qh + (size_t)(b * NHH + h) * SS * HDD;
    const _Float16* K = Kh + (size_t)(b * NHH + h) * SS * HDD;
    const _Float16* V = Vt + (size_t)(b * NHH + h) * HDD * SS;

    int qA = tA * 64 + wq * 16 + m16;
    int qB = tB * 64 + wq * 16 + m16;
    int q = myT * 64 + wq * 16 + m16;     // current q row (mask target); A switches to qB
    f16x8 aq0 = *(const f16x8*)(Q + (size_t)q * HDD + quad * 8);
    f16x8 aq1 = *(const f16x8*)(Q + (size_t)q * HDD + 32 + quad * 8);
    // helper Q-frags (qB). For B-waves qB==q -> same address, CSE'd; A-waves +16 VGPR.
    f16x8 aqH0 = *(const f16x8*)(Q + (size_t)qB * HDD + quad * 8);
    f16x8 aqH1 = *(const f16x8*)(Q + (size_t)qB * HDD + 32 + quad * 8);

    // staging: wave w covers rows [w*8, w*8+8), one 8-row instr per matrix
    int srow = w * 8 + (l >> 3);
    int sch = (l & 7) ^ (l >> 3);
    const _Float16* kg = K + (size_t)srow * HDD + sch * 8;
    const _Float16* vg = V + (size_t)srow * SS + sch * 8;

    auto stage = [&](int t, int s) {
        int kt = t * 64;
        _Float16* kb = &KV[s * 8192];
        _Float16* vb = &KV[s * 8192 + 4096];
        gl2lds16(kg + (size_t)kt * HDD, kb + (w * 8) * 64);
        gl2lds16(vg + kt, vb + (w * 8) * 64);
    };

    int swz = m16 & 7;
    int cka = (quad ^ swz) * 8;          // K-frag d-chunk 0..31
    int ckb = ((quad + 4) ^ swz) * 8;    // K-frag d-chunk 32..63
    int vco[4];
#pragma unroll
    for (int s = 0; s < 4; ++s)
        vco[s] = (((s * 2 + (quad >> 1)) ^ swz) * 8) + (quad & 1) * 4;

    f32x4 zero4 = {0.f, 0.f, 0.f, 0.f};
    const f16x4 ones4 = {(_Float16)1.f, (_Float16)1.f, (_Float16)1.f, (_Float16)1.f};
    f32x4 o[4];                          // O^T: row d=c*16+quad*4+r, col q=m16
#pragma unroll
    for (int c = 0; c < 4; ++c) o[c] = zero4;
    f32x4 lacc = zero4;                  // softmax denominator (all rows identical)

    const _Float16* kb;
    const _Float16* vb;
    int kt;

    auto body = [&](int slo, int shi) {
        f32x4 st[4];
        f16x4 pt[4];
#pragma unroll
        for (int s = 0; s < 4; ++s) {
            if (s < slo || s >= shi) continue;
            const _Float16* kr = kb + (s * 16 + m16) * 64;
            f16x8 k0 = *(const f16x8*)(kr + cka);
            f16x8 k1 = *(const f16x8*)(kr + ckb);
            st[s] = MFMA16(k0, aq0, zero4);
            st[s] = MFMA16(k1, aq1, st[s]);
        }
#pragma unroll
        for (int s = 0; s < 4; ++s) {
            if (s < slo || s >= shi) continue;
#pragma unroll
            for (int r = 0; r < 4; ++r) {
                float p = fexp2(st[s][r]);
                int key = kt + s * 16 + quad * 4 + r;
                if (key > q) p = 0.f;     // inert below the diagonal tile
                pt[s][r] = (_Float16)p;
            }
            lacc = MFMA16K16(ones4, pt[s], lacc);
        }
#pragma unroll
        for (int c = 0; c < 4; ++c) {
            const _Float16* vr = vb + (c * 16 + m16) * 64;
#pragma unroll
            for (int s = 0; s < 4; ++s) {
                if (s < slo || s >= shi) continue;
                o[c] = MFMA16K16(*(const f16x4*)(vr + vco[s]), pt[s], o[c]);
            }
        }
    };

    stage(0, 0);
    stage(1, 1);
    int cur = 0;
    for (int t = 0; t <= tB; ++t) {
        kt = t * 64;
        if (t < tB) asm volatile("s_waitcnt vmcnt(2)" ::: "memory");
        else        asm volatile("s_waitcnt vmcnt(0)" ::: "memory");
        asm volatile("s_barrier" ::: "memory");
        if (t + 2 <= tB) {
            int nxt = cur + 2; if (nxt >= 3) nxt -= 3;
            stage(t + 2, nxt);
        }

        kb = &KV[cur * 8192];
        vb = &KV[cur * 8192 + 4096];
        if (t <= tA)          body(0, 4);   // both halves: own tile, full body
        else if (half == 0)   body(0, 2);   // A helps qB: slices 0,1
        else                  body(2, 4);   // B continues qB: slices 2,3

        if (half == 0 && t == tA) {
            // qA complete: normalize + store now, free state, switch to qB helper
            float inv = 1.0f / lacc[0];
            size_t rowoff = ((size_t)(b * SS) + qA) * HH + h * HDD;
#pragma unroll
            for (int c = 0; c < 4; ++c) {
                f16x4 ov;
#pragma unroll
                for (int r = 0; r < 4; ++r) ov[r] = (_Float16)(o[c][r] * inv);
                *(f16x4*)&Ctx[rowoff + c * 16 + quad * 4] = ov;
                o[c] = zero4;
            }
            lacc = zero4;
            aq0 = aqH0; aq1 = aqH1;
            q = qB;
        }

        cur = (cur == 2) ? 0 : cur + 1;
    }

    // ---- merge qB partials: A-wave w -> B-wave w+4 (same wq => same q rows) ----
    __syncthreads();                      // all loop LDS reads done; KV reusable
    float* red = (float*)KV;              // 256 lanes x 17 f32 = 17408 B < 49152
    if (half == 0) {
        float* slot = red + (size_t)(w * 64 + l) * 17;   // stride 17: conflict-free
#pragma unroll
        for (int c = 0; c < 4; ++c)
#pragma unroll
            for (int r = 0; r < 4; ++r) slot[c * 4 + r] = o[c][r];
        slot[16] = lacc[0];
    }
    __syncthreads();
    if (half == 1) {
        const float* slot = red + (size_t)((w - 4) * 64 + l) * 17;
        float lf = lacc[0] + slot[16];
        float inv = 1.0f / lf;
        size_t rowoff = ((size_t)(b * SS) + q) * HH + h * HDD;
#pragma unroll
        for (int c = 0; c < 4; ++c) {
            f16x4 ov;
#pragma unroll
            for (int r = 0; r < 4; ++r)
                ov[r] = (_Float16)((o[c][r] + slot[c * 4 + r]) * inv);
            *(f16x4*)&Ctx[rowoff + c * 16 + quad * 4] = ov;
        }
    }
}

extern "C" void kernel_launch(void* const* d_in, const int* in_sizes, int n_in,
                              void* d_out, int out_size, void* d_ws, size_t ws_size,
                              hipStream_t stream) {
    const float* hs = (const float*)d_in[0];
    const float* Wq = (const float*)d_in[1];
    const float* bq = (const float*)d_in[2];
    const float* Wk = (const float*)d_in[3];
    const float* bk = (const float*)d_in[4];
    const float* Wv = (const float*)d_in[5];
    const float* bv = (const float*)d_in[6];
    const float* Wo = (const float*)d_in[7];
    const float* bo = (const float*)d_in[8];
    float* out = (float*)d_out;

    size_t off = 0;
    auto alloc = [&](size_t bytes) {
        void* p = (char*)d_ws + off;
        off += (bytes + 255) & ~(size_t)255;
        return p;
    };
    _Float16* Xh    = (_Float16*)alloc((size_t)MM * HH * 2);
    _Float16* WqkvT = (_Float16*)alloc((size_t)3 * HH * HH * 2);
    _Float16* WoT   = (_Float16*)alloc((size_t)HH * HH * 2);
    _Float16* Qh    = (_Float16*)alloc((size_t)BB * NHH * SS * HDD * 2);
    _Float16* Kh    = (_Float16*)alloc((size_t)BB * NHH * SS * HDD * 2);
    _Float16* Vt    = (_Float16*)alloc((size_t)BB * NHH * SS * HDD * 2);
    _Float16* Ctx   = (_Float16*)alloc((size_t)MM * HH * 2);

    prep_kernel<<<dim3(16, 16, 5), 256, 0, stream>>>(
        hs, Wq, Wk, Wv, Wo, Xh, WqkvT, WoT);
    gemm_qkv_kernel<<<dim3(QKV_N / 128, MM / 128), 256, 0, stream>>>(
        Xh, WqkvT, bq, bk, bv, Qh, Kh, Vt);
    attn_kernel<<<dim3(16, NHH, BB), 512, 0, stream>>>(Qh, Kh, Vt, Ctx);
    gemm_out_kernel<<<dim3(HH / 128, MM / 128), 512, 0, stream>>>(
        Ctx, WoT, bo, out);
}

// Round 12
// 178.957 us; speedup vs baseline: 1.0648x; 1.0648x over previous
//
#include <hip/hip_runtime.h>
#include <hip/hip_bf16.h>

// Problem constants
#define BB 2
#define SS 2048
#define HH 1024
#define NHH 16
#define HDD 64
#define MM (BB*SS)        // 4096
#define QKV_N (3*HH)      // 3072

typedef _Float16 f16x8 __attribute__((ext_vector_type(8)));
typedef _Float16 f16x4 __attribute__((ext_vector_type(4)));
typedef float f32x4 __attribute__((ext_vector_type(4)));

#define MFMA16(a,b,c)  __builtin_amdgcn_mfma_f32_16x16x32_f16((a),(b),(c),0,0,0)
#define MFMA16K16(a,b,c) __builtin_amdgcn_mfma_f32_16x16x16f16((a),(b),(c),0,0,0)

// async global->LDS 16B per lane; LDS dest = wave-uniform base + lane*16
__device__ __forceinline__ void gl2lds16(const _Float16* g, _Float16* l) {
    __builtin_amdgcn_global_load_lds(
        (const __attribute__((address_space(1))) void*)g,
        (__attribute__((address_space(3))) void*)l, 16, 0, 0);
}

// single-instruction exp2 WITH compiler hazard handling (raw asm broke TRANS-op waits)
__device__ __forceinline__ float fexp2(float x) { return __builtin_amdgcn_exp2f(x); }

// ---------------- prep: z<4 transpose-cast W -> Wt fp16; z==4 cast X -> fp16 ------------
// grid (16,16,5), block 256.
__global__ __launch_bounds__(256) void prep_kernel(
    const float* __restrict__ X,
    const float* __restrict__ W0, const float* __restrict__ W1,
    const float* __restrict__ W2, const float* __restrict__ W3,
    _Float16* __restrict__ Xh,
    _Float16* __restrict__ WqkvT, _Float16* __restrict__ WoT)
{
    __shared__ float t[64][65];
    int z = blockIdx.z;
    int tid = threadIdx.x;
    if (z == 4) {
        int base = (blockIdx.y * 16 + blockIdx.x) * 256 + tid;
        const float4* xin = (const float4*)X;
        f16x4* xout = (f16x4*)Xh;
#pragma unroll
        for (int i = 0; i < 16; ++i) {
            float4 v = xin[base + i * 65536];
            f16x4 hh = {(_Float16)v.x, (_Float16)v.y, (_Float16)v.z, (_Float16)v.w};
            xout[base + i * 65536] = hh;
        }
        return;
    }
    const float* src = (z == 0) ? W0 : (z == 1) ? W1 : (z == 2) ? W2 : W3;
    _Float16* dst = (z < 3) ? (WqkvT + (size_t)z * HH * HH) : WoT;
    int k0 = blockIdx.y * 64, n0 = blockIdx.x * 64;
#pragma unroll
    for (int p = 0; p < 4; ++p) {
        int row = p * 16 + (tid >> 4);
        int col4 = (tid & 15) * 4;
        float4 v = *(const float4*)&src[(size_t)(k0 + row) * HH + n0 + col4];
        t[row][col4 + 0] = v.x; t[row][col4 + 1] = v.y;
        t[row][col4 + 2] = v.z; t[row][col4 + 3] = v.w;
    }
    __syncthreads();
#pragma unroll
    for (int p = 0; p < 2; ++p) {
        int nc = p * 32 + (tid >> 3);
        int ch = tid & 7;
        f16x8 o;
#pragma unroll
        for (int j = 0; j < 8; ++j) o[j] = (_Float16)t[ch * 8 + j][nc];
        *(f16x8*)&dst[(size_t)(n0 + nc) * HH + k0 + ch * 8] = o;
    }
}

// ---------------- QKV GEMM: 128x128 tile, 3-stage pipeline (proven 43.5us) --------------
// + XCD-chunked swizzle: grid 768 = 8x96; each XCD gets 96 contiguous work items =
// 4 A-panel rows x 24 col-tiles -> A fetched once per XCD L2 instead of 8x
// (FETCH was 35.9 MB vs 14 MB compulsory = cross-XCD replication).
__global__ __launch_bounds__(256) void gemm_qkv_kernel(
    const _Float16* __restrict__ A, const _Float16* __restrict__ Bt,
    const float* __restrict__ bias0, const float* __restrict__ bias1, const float* __restrict__ bias2,
    _Float16* __restrict__ Qh, _Float16* __restrict__ Kh, _Float16* __restrict__ Vt)
{
    const int K = HH;
    const int NT = K / 32;
    __shared__ _Float16 smem[24576];          // 49152 B: 3-stage bufs U epilogue tile 128x132

    int flat = blockIdx.x + blockIdx.y * 24;  // grid (24, 32) = 768 = 8 * 96
    int wid = (flat & 7) * 96 + (flat >> 3);  // bijective XCD chunking
    int bx = wid % 24, by = wid / 24;
    int row0 = by * 128, n0 = bx * 128;
    int tid = threadIdx.x;
    int w = tid >> 6, l = tid & 63, m16 = l & 15, quad = l >> 4;
    int wm = w >> 1, wn = w & 1;

    int srow = w * 32 + (l >> 2);
    int sch = (l & 3) ^ ((l >> 2) & 3) ^ ((l >> 4) & 3);
    const _Float16* aptr = A + (size_t)(row0 + srow) * K + sch * 8;
    const _Float16* bptr = Bt + (size_t)(n0 + srow) * K + sch * 8;

    int gsw = (m16 & 3) ^ ((m16 >> 2) & 3);
    int acol = (quad ^ gsw) * 8;

    f32x4 zero4 = {0.f, 0.f, 0.f, 0.f};
    f32x4 acc[4][4];
#pragma unroll
    for (int i = 0; i < 4; ++i)
#pragma unroll
        for (int j = 0; j < 4; ++j) acc[i][j] = zero4;

    auto stage = [&](int t, int s) {
        int k0 = t * 32;
        int ao = s * 4096 + (w * 32) * 32;
        int bo = 12288 + s * 4096 + (w * 32) * 32;
        gl2lds16(aptr + k0, smem + ao);
        gl2lds16(aptr + (size_t)16 * K + k0, smem + ao + 16 * 32);
        gl2lds16(bptr + k0, smem + bo);
        gl2lds16(bptr + (size_t)16 * K + k0, smem + bo + 16 * 32);
    };

    stage(0, 0);
    stage(1, 1);
    int cur = 0;
    for (int t = 0; t < NT; ++t) {
        if (t < NT - 1) asm volatile("s_waitcnt vmcnt(4)" ::: "memory");
        else            asm volatile("s_waitcnt vmcnt(0)" ::: "memory");
        asm volatile("s_barrier" ::: "memory");
        if (t + 2 < NT) {
            int nxt = cur + 2; if (nxt >= 3) nxt -= 3;
            stage(t + 2, nxt);
        }
        const _Float16* Asr = smem + cur * 4096;
        const _Float16* Bsr = smem + 12288 + cur * 4096;
        f16x8 af[4], bf[4];
#pragma unroll
        for (int i = 0; i < 4; ++i)
            af[i] = *(const f16x8*)&Asr[(wm * 64 + i * 16 + m16) * 32 + acol];
#pragma unroll
        for (int j = 0; j < 4; ++j)
            bf[j] = *(const f16x8*)&Bsr[(wn * 64 + j * 16 + m16) * 32 + acol];
#pragma unroll
        for (int i = 0; i < 4; ++i)
#pragma unroll
            for (int j = 0; j < 4; ++j)
                acc[i][j] = MFMA16(af[i], bf[j], acc[i][j]);
        cur = (cur == 2) ? 0 : cur + 1;
    }

    // ---- epilogue: bias (+scale for Q), LDS bounce, coalesced stores ----
    int which = n0 >> 10;                     // 0=Q 1=K 2=V (block is pure)
    const float* bias = (which == 0) ? bias0 : (which == 1) ? bias1 : bias2;
    __syncthreads();
#pragma unroll
    for (int j = 0; j < 4; ++j) {
        int n_local = wn * 64 + j * 16 + m16;
        float bi = bias[(n0 + n_local) & 1023];
#pragma unroll
        for (int i = 0; i < 4; ++i)
#pragma unroll
            for (int r = 0; r < 4; ++r) {
                int m_local = wm * 64 + i * 16 + quad * 4 + r;
                float v = acc[i][j][r] + bi;
                if (which == 0) v *= 0.18033688011112042f;  // (1/sqrt(64))*log2(e)
                if (which == 2) smem[n_local * 132 + m_local] = (_Float16)v;   // transposed
                else            smem[m_local * 132 + n_local] = (_Float16)v;
            }
    }
    __syncthreads();

    int b = row0 >> 11, s0 = row0 & 2047;
    if (which == 2) {
#pragma unroll
        for (int p = 0; p < 8; ++p) {
            int n_local = p * 16 + (tid >> 4);
            int schunk = tid & 15;
            f16x8 v = *(const f16x8*)&smem[n_local * 132 + schunk * 8];
            int nw = (n0 + n_local) & 1023;
            int hh = nw >> 6, d = nw & 63;
            *(f16x8*)&Vt[((size_t)(b * NHH + hh) * HDD + d) * SS + s0 + schunk * 8] = v;
        }
    } else {
        _Float16* dst = (which == 0) ? Qh : Kh;
        int hh0 = (n0 & 1023) >> 6;
#pragma unroll
        for (int p = 0; p < 8; ++p) {
            int m_local = p * 16 + (tid >> 4);
            int seg = tid & 15;
            f16x8 v = *(const f16x8*)&smem[m_local * 132 + seg * 8];
            int hh = hh0 + (seg >> 3), d = (seg & 7) * 8;
            *(f16x8*)&dst[((size_t)(b * NHH + hh) * SS + s0 + m_local) * HDD + d] = v;
        }
    }
}

// ---------------- Output projection: 128x128 tile, split-K WITHIN block (proven R10) ----
// + XCD-chunked swizzle: grid 256 = 8x32; each XCD: 8 col-tiles x 4 row-panels
// (Ctx panel reused 8x within its XCD L2; WoT 2MB L2-resident).
__global__ __launch_bounds__(512, 2) void gemm_out_kernel(
    const _Float16* __restrict__ A, const _Float16* __restrict__ Bt,
    const float* __restrict__ bias0, float* __restrict__ Out)
{
    const int K = HH;
    const int NT = 16;                        // 16 x 32 = 512 of K per group
    __shared__ _Float16 smem[49152];          // 98304 B: group g 3-stage bufs at g*24576

    int flat = blockIdx.x + (blockIdx.y << 3);    // grid (8, 32) = 256 = 8 * 32
    int wid = (flat & 7) * 32 + (flat >> 3);
    int row0 = (wid >> 3) * 128, n0 = (wid & 7) * 128;
    int tid = threadIdx.x;
    int w = tid >> 6, l = tid & 63, m16 = l & 15, quad = l >> 4;
    int kg = w >> 2, wl = w & 3;              // K-group, wave-in-group
    int wm = wl >> 1, wn = wl & 1;
    int kbase = kg * 512;
    _Float16* gsm = smem + kg * 24576;

    int srow = wl * 32 + (l >> 2);
    int sch = (l & 3) ^ ((l >> 2) & 3) ^ ((l >> 4) & 3);
    const _Float16* aptr = A + (size_t)(row0 + srow) * K + kbase + sch * 8;
    const _Float16* bptr = Bt + (size_t)(n0 + srow) * K + kbase + sch * 8;

    int gsw = (m16 & 3) ^ ((m16 >> 2) & 3);
    int acol = (quad ^ gsw) * 8;

    f32x4 zero4 = {0.f, 0.f, 0.f, 0.f};
    f32x4 acc[4][4];
#pragma unroll
    for (int i = 0; i < 4; ++i)
#pragma unroll
        for (int j = 0; j < 4; ++j) acc[i][j] = zero4;

    auto stage = [&](int t, int s) {
        int k0 = t * 32;
        int ao = s * 4096 + (wl * 32) * 32;
        int bo = 12288 + s * 4096 + (wl * 32) * 32;
        gl2lds16(aptr + k0, gsm + ao);
        gl2lds16(aptr + (size_t)16 * K + k0, gsm + ao + 16 * 32);
        gl2lds16(bptr + k0, gsm + bo);
        gl2lds16(bptr + (size_t)16 * K + k0, gsm + bo + 16 * 32);
    };

    stage(0, 0);
    stage(1, 1);
    int cur = 0;
    for (int t = 0; t < NT; ++t) {
        if (t < NT - 1) asm volatile("s_waitcnt vmcnt(4)" ::: "memory");
        else            asm volatile("s_waitcnt vmcnt(0)" ::: "memory");
        asm volatile("s_barrier" ::: "memory");
        if (t + 2 < NT) {
            int nxt = cur + 2; if (nxt >= 3) nxt -= 3;
            stage(t + 2, nxt);
        }
        const _Float16* Asr = gsm + cur * 4096;
        const _Float16* Bsr = gsm + 12288 + cur * 4096;
        f16x8 af[4], bf[4];
#pragma unroll
        for (int i = 0; i < 4; ++i)
            af[i] = *(const f16x8*)&Asr[(wm * 64 + i * 16 + m16) * 32 + acol];
#pragma unroll
        for (int j = 0; j < 4; ++j)
            bf[j] = *(const f16x8*)&Bsr[(wn * 64 + j * 16 + m16) * 32 + acol];
#pragma unroll
        for (int i = 0; i < 4; ++i)
#pragma unroll
            for (int j = 0; j < 4; ++j)
                acc[i][j] = MFMA16(af[i], bf[j], acc[i][j]);
        cur = (cur == 2) ? 0 : cur + 1;
    }

    // ---- cross-group reduce: stride-65 f32 slots (conflict-free scalar access) ----
    float* red = (float*)smem;                // 256 lanes x 65 f32 = 66560 B < 98304
    __syncthreads();                          // all waves done with staging-buffer reads
    if (kg == 1) {
        float* slot = red + (size_t)(wl * 64 + l) * 65;
#pragma unroll
        for (int i = 0; i < 4; ++i)
#pragma unroll
            for (int j = 0; j < 4; ++j)
#pragma unroll
                for (int r = 0; r < 4; ++r)
                    slot[i * 16 + j * 4 + r] = acc[i][j][r];
    }
    __syncthreads();
    if (kg == 0) {
        const float* slot = red + (size_t)(wl * 64 + l) * 65;
#pragma unroll
        for (int j = 0; j < 4; ++j) {
            int n = n0 + wn * 64 + j * 16 + m16;
            float bi = bias0[n];
#pragma unroll
            for (int i = 0; i < 4; ++i)
#pragma unroll
                for (int r = 0; r < 4; ++r) {
                    int mg = row0 + wm * 64 + i * 16 + quad * 4 + r;
                    Out[(size_t)mg * HH + n] = acc[i][j][r] + slot[i * 16 + j * 4 + r] + bi;
                }
        }
    }
}

// ---------------- Flash attention: S^T formulation, 8-wave tile-split (proven ~32us) ----
// grid (16, NH, B), block 512. REVERTED to the proven paired kernel (the helper
// slice-split variant hit 52us: unconditional mask + lambda codegen raised VALUBusy
// 24->39 on the common path — fourth failed attn variant; structure search closed).
// + XCD-chunked swizzle: 512 blocks = 8x64; each XCD gets 4 COMPLETE heads (2MB K/V,
// L2-resident) — FETCH was 62MB vs ~24MB compulsory from 8x K/V replication.
__global__ __launch_bounds__(512, 4) void attn_kernel(
    const _Float16* __restrict__ Qh, const _Float16* __restrict__ Kh,
    const _Float16* __restrict__ Vt, _Float16* __restrict__ Ctx)
{
    __shared__ _Float16 KV[3 * 8192];     // 49152 B, 3-stage K+V

    int tid = threadIdx.x;
    int w = tid >> 6, l = tid & 63;
    int m16 = l & 15, quad = l >> 4;
    int flat = blockIdx.x + (blockIdx.y << 4) + (blockIdx.z << 8);  // 512 = 8 * 64
    int wid = (flat & 7) * 64 + (flat >> 3);  // bijective XCD chunking
    int tA = wid & 15, tB = 31 - tA;
    int h = (wid >> 4) & 15, b = wid >> 8;
    int half = w >> 2, wq = w & 3;
    int myT = half ? tB : tA;             // this wave's q-tile index

    const _Float16* Q = Qh + (size_t)(b * NHH + h) * SS * HDD;
    const _Float16* K = Kh + (size_t)(b * NHH + h) * SS * HDD;
    const _Float16* V = Vt + (size_t)(b * NHH + h) * HDD * SS;

    int q = myT * 64 + wq * 16 + m16;     // this lane's q row (S^T: q = lane&15)
    f16x8 aq0 = *(const f16x8*)(Q + (size_t)q * HDD + quad * 8);
    f16x8 aq1 = *(const f16x8*)(Q + (size_t)q * HDD + 32 + quad * 8);

    // staging: wave w covers rows [w*8, w*8+8), one 8-row instr per matrix
    int srow = w * 8 + (l >> 3);
    int sch = (l & 7) ^ (l >> 3);
    const _Float16* kg = K + (size_t)srow * HDD + sch * 8;
    const _Float16* vg = V + (size_t)srow * SS + sch * 8;

    auto stage = [&](int t, int s) {
        int kt = t * 64;
        _Float16* kb = &KV[s * 8192];
        _Float16* vb = &KV[s * 8192 + 4096];
        gl2lds16(kg + (size_t)kt * HDD, kb + (w * 8) * 64);
        gl2lds16(vg + kt, vb + (w * 8) * 64);
    };

    int swz = m16 & 7;
    int cka = (quad ^ swz) * 8;          // K-frag d-chunk 0..31
    int ckb = ((quad + 4) ^ swz) * 8;    // K-frag d-chunk 32..63
    int vco[4];
#pragma unroll
    for (int s = 0; s < 4; ++s)
        vco[s] = (((s * 2 + (quad >> 1)) ^ swz) * 8) + (quad & 1) * 4;

    f32x4 zero4 = {0.f, 0.f, 0.f, 0.f};
    const f16x4 ones4 = {(_Float16)1.f, (_Float16)1.f, (_Float16)1.f, (_Float16)1.f};
    f32x4 o[4];                          // O^T: row d=c*16+quad*4+r, col q=m16
#pragma unroll
    for (int c = 0; c < 4; ++c) o[c] = zero4;
    f32x4 lacc = zero4;                  // softmax denominator (all rows identical)

    stage(0, 0);
    stage(1, 1);
    int cur = 0;
    for (int t = 0; t <= tB; ++t) {
        int kt = t * 64;
        if (t < tB) asm volatile("s_waitcnt vmcnt(2)" ::: "memory");
        else        asm volatile("s_waitcnt vmcnt(0)" ::: "memory");
        asm volatile("s_barrier" ::: "memory");
        if (t + 2 <= tB) {
            int nxt = cur + 2; if (nxt >= 3) nxt -= 3;
            stage(t + 2, nxt);
        }

        if (t <= myT) {                   // wave-uniform: body only while tile active
            const _Float16* kb = &KV[cur * 8192];
            const _Float16* vb = &KV[cur * 8192 + 4096];
            f16x8 bk[4][2];
#pragma unroll
            for (int s = 0; s < 4; ++s) {
                const _Float16* kr = kb + (s * 16 + m16) * 64;
                bk[s][0] = *(const f16x8*)(kr + cka);
                bk[s][1] = *(const f16x8*)(kr + ckb);
            }
            f16x4 av[4][4];              // [c d-block][s key-chunk]
#pragma unroll
            for (int c = 0; c < 4; ++c) {
                const _Float16* vr = vb + (c * 16 + m16) * 64;
#pragma unroll
                for (int s = 0; s < 4; ++s)
                    av[c][s] = *(const f16x4*)(vr + vco[s]);
            }

            f32x4 st[4];
#pragma unroll
            for (int s = 0; s < 4; ++s) {
                st[s] = MFMA16(bk[s][0], aq0, zero4);
                st[s] = MFMA16(bk[s][1], aq1, st[s]);
            }
            f16x4 pt[4];
            if (t == myT) {              // masked (diagonal) tile
#pragma unroll
                for (int s = 0; s < 4; ++s)
#pragma unroll
                    for (int r = 0; r < 4; ++r) {
                        float p = fexp2(st[s][r]);
                        int key = kt + s * 16 + quad * 4 + r;
                        if (key > q) p = 0.f;
                        pt[s][r] = (_Float16)p;
                    }
            } else {
#pragma unroll
                for (int s = 0; s < 4; ++s)
#pragma unroll
                    for (int r = 0; r < 4; ++r)
                        pt[s][r] = (_Float16)fexp2(st[s][r]);
            }
#pragma unroll
            for (int s = 0; s < 4; ++s)
                lacc = MFMA16K16(ones4, pt[s], lacc);
#pragma unroll
            for (int c = 0; c < 4; ++c)
#pragma unroll
                for (int s = 0; s < 4; ++s)
                    o[c] = MFMA16K16(av[c][s], pt[s], o[c]);
        }

        cur = (cur == 2) ? 0 : cur + 1;
    }

    // epilogue: normalize (denominator identical across rows/quads for a given q), store O^T
    float inv = 1.0f / lacc[0];
    size_t rowoff = ((size_t)(b * SS) + q) * HH + h * HDD;
#pragma unroll
    for (int c = 0; c < 4; ++c) {
        f16x4 ov;
#pragma unroll
        for (int r = 0; r < 4; ++r) ov[r] = (_Float16)(o[c][r] * inv);
        *(f16x4*)&Ctx[rowoff + c * 16 + quad * 4] = ov;
    }
}

extern "C" void kernel_launch(void* const* d_in, const int* in_sizes, int n_in,
                              void* d_out, int out_size, void* d_ws, size_t ws_size,
                              hipStream_t stream) {
    const float* hs = (const float*)d_in[0];
    const float* Wq = (const float*)d_in[1];
    const float* bq = (const float*)d_in[2];
    const float* Wk = (const float*)d_in[3];
    const float* bk = (const float*)d_in[4];
    const float* Wv = (const float*)d_in[5];
    const float* bv = (const float*)d_in[6];
    const float* Wo = (const float*)d_in[7];
    const float* bo = (const float*)d_in[8];
    float* out = (float*)d_out;

    size_t off = 0;
    auto alloc = [&](size_t bytes) {
        void* p = (char*)d_ws + off;
        off += (bytes + 255) & ~(size_t)255;
        return p;
    };
    _Float16* Xh    = (_Float16*)alloc((size_t)MM * HH * 2);
    _Float16* WqkvT = (_Float16*)alloc((size_t)3 * HH * HH * 2);
    _Float16* WoT   = (_Float16*)alloc((size_t)HH * HH * 2);
    _Float16* Qh    = (_Float16*)alloc((size_t)BB * NHH * SS * HDD * 2);
    _Float16* Kh    = (_Float16*)alloc((size_t)BB * NHH * SS * HDD * 2);
    _Float16* Vt    = (_Float16*)alloc((size_t)BB * NHH * SS * HDD * 2);
    _Float16* Ctx   = (_Float16*)alloc((size_t)MM * HH * 2);

    prep_kernel<<<dim3(16, 16, 5), 256, 0, stream>>>(
        hs, Wq, Wk, Wv, Wo, Xh, WqkvT, WoT);
    gemm_qkv_kernel<<<dim3(QKV_N / 128, MM / 128), 256, 0, stream>>>(
        Xh, WqkvT, bq, bk, bv, Qh, Kh, Vt);
    attn_kernel<<<dim3(16, NHH, BB), 512, 0, stream>>>(Qh, Kh, Vt, Ctx);
    gemm_out_kernel<<<dim3(HH / 128, MM / 128), 512, 0, stream>>>(
        Ctx, WoT, bo, out);
}